// Round 9
// baseline (300.897 us; speedup 1.0000x reference)
//
#include <hip/hip_runtime.h>
#include <math.h>
#include <stdint.h>

// UpsampleFlow3: fused exact 5-NN + softmax(-dist) + weighted flow sum.
// B=4, N=16384, M=4096, K=5, fp32.
//
// Round-11 (post-mortem r10: walk-prune over 64 SPREAD lanes never fires ->
// wide groups still cost ~13.8K insts/wave; grid path never beat brute total
// because prep ate the knn savings):
//  - SUPER-CELL GROUPING: queries grouped by Morton super-cell (2x2x2 cells,
//    code>>6; contiguous in sorted order). Every wave's queries span <=2
//    cells/axis -> coherent per-lane pruning everywhere; wide-span branch
//    DELETED. Partial waves mirror the last query (no writes).
//  - FIXED GRID BOX [-4,4]^3 (h=1) with INFINITE-EXTENT EDGE CELLS in all
//    mindist tests (outliers clamp into edge cells; infinity extends only
//    outward so every bound stays conservative -> exact).
//  - prep collapsed to ONE 4-block LDS kernel: hist + scan + scatter +
//    deterministic per-batch group table. No bbox, no memset. 2 launches.
//  - knn: per-lane home-cell warm-up bound bw; phase-1 span scan + expanding
//    rings, per-lane prune with min(e4,bw)+qq; no atomics, no mid barriers.

#define KNN 5
#define GRID 8
#define NCELL (GRID * GRID * GRID)
#define SLICES 8
#define BLOCK (SLICES * 64)
#define BOXLO -4.0f
#define EPSM 1e-3f

typedef unsigned int u32;

__device__ __forceinline__ float get_inv_sigma(const int* __restrict__ rf) {
    const int ri = rf[0];
    const float sigma = (ri >= 1 && ri <= 1000000) ? (float)ri : __int_as_float(ri);
    return 1.0f / sigma;
}

__device__ __forceinline__ float rfl_f(float v) {
    return __int_as_float(__builtin_amdgcn_readfirstlane(__float_as_int(v)));
}

// fixed-box cell id along one axis (h = 1.0)
__device__ __forceinline__ int cidf(float x) {
    const int c = (int)floorf(x - BOXLO);
    return c < 0 ? 0 : (c > GRID - 1 ? GRID - 1 : c);
}

// 3-bit Morton spread: bit i -> bit 3i
__device__ __forceinline__ int sp3(int v) {
    return (v & 1) | ((v & 2) << 2) | ((v & 4) << 4);
}

__device__ __forceinline__ int cellf(float x, float y, float z) {
    return (sp3(cidf(x)) << 2) | (sp3(cidf(y)) << 1) | sp3(cidf(z));
}

// per-axis distance from q to cell c's slab; edge cells extend to infinity
// (clamped outliers live there, so this is the exact conservative bound).
__device__ __forceinline__ float axdist(float q, int c) {
    const float lo = (c == 0) ? -1e30f : (BOXLO + (float)c);
    const float hi = (c == GRID - 1) ? 1e30f : (BOXLO + (float)(c + 1));
    const float cq = fminf(fmaxf(q, lo), hi);
    return q - cq;
}

// Compare-exchange: insert candidate (c,ci) into slot (k,ki); larger goes on.
#define CE_FULL(k, ki, c, ci)                          \
    {                                                  \
        const bool sw = (c) < (k);                     \
        const float vmn = fminf(k, c);                 \
        const float vmx = fmaxf(k, c);                 \
        const u32 nki = sw ? (ci) : (ki);              \
        const u32 nci = sw ? (ki) : (ci);              \
        (k) = vmn; (c) = vmx; (ki) = nki; (ci) = nci;  \
    }
#define CE_LAST(k, ki, c, ci)                          \
    {                                                  \
        const bool sw = (c) < (k);                     \
        (ki) = sw ? (ci) : (ki);                       \
        (k) = fminf(k, c);                             \
    }

// exact ladder on d2' = |p|^2 - 2 q.p (qq deferred; order preserved)
#define LAD(P, CI)                                     \
    {                                                  \
        float t_ = qx * (P).x;                         \
        t_ = fmaf(qy, (P).y, t_);                      \
        t_ = fmaf(qz, (P).z, t_);                      \
        float c_ = fmaf(-2.0f, t_, (P).w);             \
        u32 ci_ = (u32)(CI);                           \
        CE_FULL(e0, i0, c_, ci_)                       \
        CE_FULL(e1, i1, c_, ci_)                       \
        CE_FULL(e2, i2, c_, ci_)                       \
        CE_FULL(e3, i3, c_, ci_)                       \
        CE_LAST(e4, i4, c_, ci_)                       \
    }

// ---------------- legacy brute path (ws-too-small fallback) ----------------

__global__ __launch_bounds__(256)
void prep_kernel(const float* __restrict__ sxyz, const int* __restrict__ rf,
                 float4* __restrict__ pts, int M, int total) {
    const int t = blockIdx.x * 256 + threadIdx.x;
    if (t >= total) return;
    const float inv = get_inv_sigma(rf);
    const int b = t / M, m = t - b * M;
    const float* sb = sxyz + (size_t)b * 3 * M;
    const float x = sb[m] * inv;
    const float y = sb[M + m] * inv;
    const float z = sb[2 * M + m] * inv;
    pts[t] = make_float4(x, y, z, fmaf(x, x, fmaf(y, y, z * z)));
}

template <bool USE_PTS>
__global__ __launch_bounds__(BLOCK, 8)
void knn_kernel(const float* __restrict__ xyz,
                const float* __restrict__ sxyz,
                const float* __restrict__ sflow,
                const int* __restrict__ rf,
                const float4* __restrict__ pts,
                float* __restrict__ out,
                int N, int M) {
    __shared__ float sval_d[SLICES * KNN * 64];
    __shared__ u32   sval_i[SLICES * KNN * 64];

    const int tid  = threadIdx.x;
    const int lane = tid & 63;
    const int wid  = tid >> 6;
    const int swid = __builtin_amdgcn_readfirstlane(wid);
    const int gpb  = N / 64;
    const int b    = blockIdx.x / gpb;
    const int grp  = blockIdx.x - b * gpb;
    const int n    = grp * 64 + lane;

    const float inv = get_inv_sigma(rf);
    const float* qb = xyz + (size_t)b * 3 * N;
    const float qx = qb[n] * inv;
    const float qy = qb[N + n] * inv;
    const float qz = qb[2 * N + n] * inv;
    const float qq = fmaf(qx, qx, fmaf(qy, qy, qz * qz));

    const int CH = M / SLICES;
    const int j0 = swid * CH;

    float e0 = 1e30f, e1 = 1e30f, e2 = 1e30f, e3 = 1e30f, e4 = 1e30f;
    u32   i0 = 0, i1 = 0, i2 = 0, i3 = 0, i4 = 0;

    if constexpr (USE_PTS) {
        const float4* __restrict__ P = pts + (size_t)b * M + j0;
#pragma unroll 4
        for (int j = 0; j < CH; ++j) {
            const float4 p = P[j];
            LAD(p, j0 + j)
        }
    } else {
        const float* __restrict__ sb = sxyz + (size_t)b * 3 * M;
#pragma unroll 4
        for (int j = 0; j < CH; ++j) {
            const float px = sb[j0 + j] * inv;
            const float py = sb[M + j0 + j] * inv;
            const float pz = sb[2 * M + j0 + j] * inv;
            const float pw = fmaf(px, px, fmaf(py, py, pz * pz));
            const float4 p = make_float4(px, py, pz, pw);
            LAD(p, j0 + j)
        }
    }

    sval_d[(wid * KNN + 0) * 64 + lane] = e0;  sval_i[(wid * KNN + 0) * 64 + lane] = i0;
    sval_d[(wid * KNN + 1) * 64 + lane] = e1;  sval_i[(wid * KNN + 1) * 64 + lane] = i1;
    sval_d[(wid * KNN + 2) * 64 + lane] = e2;  sval_i[(wid * KNN + 2) * 64 + lane] = i2;
    sval_d[(wid * KNN + 3) * 64 + lane] = e3;  sval_i[(wid * KNN + 3) * 64 + lane] = i3;
    sval_d[(wid * KNN + 4) * 64 + lane] = e4;  sval_i[(wid * KNN + 4) * 64 + lane] = i4;
    __syncthreads();

    if (wid == 0) {
        float m0 = 1e30f, m1 = 1e30f, m2 = 1e30f, m3 = 1e30f, m4 = 1e30f;
        u32   g0 = 0, g1 = 0, g2 = 0, g3 = 0, g4 = 0;
#pragma unroll
        for (int w = 0; w < SLICES; ++w) {
#pragma unroll
            for (int k = 0; k < KNN; ++k) {
                float c = sval_d[(w * KNN + k) * 64 + lane];
                u32  ci = sval_i[(w * KNN + k) * 64 + lane];
                CE_FULL(m0, g0, c, ci)
                CE_FULL(m1, g1, c, ci)
                CE_FULL(m2, g2, c, ci)
                CE_FULL(m3, g3, c, ci)
                CE_LAST(m4, g4, c, ci)
            }
        }

        const float d0 = sqrtf(fmaxf(m0 + qq, 1e-12f));
        const float d1 = sqrtf(fmaxf(m1 + qq, 1e-12f));
        const float d2 = sqrtf(fmaxf(m2 + qq, 1e-12f));
        const float d3 = sqrtf(fmaxf(m3 + qq, 1e-12f));
        const float d4 = sqrtf(fmaxf(m4 + qq, 1e-12f));
        const float w0 = 1.0f;
        const float w1 = expf(d0 - d1);
        const float w2 = expf(d0 - d2);
        const float w3 = expf(d0 - d3);
        const float w4 = expf(d0 - d4);
        const float inv_wsum = 1.0f / (w0 + w1 + w2 + w3 + w4);

        const float* fb = sflow + (size_t)b * 3 * M;
        float ax = 0.f, ay = 0.f, az = 0.f;
        ax = fmaf(w0, fb[g0], ax); ay = fmaf(w0, fb[M + g0], ay); az = fmaf(w0, fb[2 * M + g0], az);
        ax = fmaf(w1, fb[g1], ax); ay = fmaf(w1, fb[M + g1], ay); az = fmaf(w1, fb[2 * M + g1], az);
        ax = fmaf(w2, fb[g2], ax); ay = fmaf(w2, fb[M + g2], ay); az = fmaf(w2, fb[2 * M + g2], az);
        ax = fmaf(w3, fb[g3], ax); ay = fmaf(w3, fb[M + g3], ay); az = fmaf(w3, fb[2 * M + g3], az);
        ax = fmaf(w4, fb[g4], ax); ay = fmaf(w4, fb[M + g4], ay); az = fmaf(w4, fb[2 * M + g4], az);

        float* ob = out + (size_t)b * 3 * N;
        ob[n]         = ax * inv_wsum;
        ob[N + n]     = ay * inv_wsum;
        ob[2 * N + n] = az * inv_wsum;
    }
}

// ---------------- fused prep: hist + scan + scatter + group table ----------------
// One block per batch. Fixed grid box -> no bbox pass, no global hist, no memset.

__global__ __launch_bounds__(1024)
void prep_cell_kernel(const float* __restrict__ xyz, const float* __restrict__ sxyz,
                      const int* __restrict__ rf, int2* __restrict__ off2C,
                      float4* __restrict__ ptsS, float4* __restrict__ qS,
                      int* __restrict__ idxS, int2* __restrict__ grpTab,
                      int* __restrict__ grpCnt, int N, int M, int GPB) {
    __shared__ int hC[NCELL], hQ[NCELL];
    __shared__ int oC[NCELL], oQ[NCELL];
    __shared__ int sQex[NCELL];

    const int b = blockIdx.x, t = threadIdx.x;
    const float inv = get_inv_sigma(rf);
    const float* sb = sxyz + (size_t)b * 3 * M;
    const float* qb = xyz + (size_t)b * 3 * N;

    for (int c = t; c < NCELL; c += 1024) { hC[c] = 0; hQ[c] = 0; }
    __syncthreads();

    // hist
    for (int m = t; m < M; m += 1024) {
        const float x = sb[m] * inv, y = sb[M + m] * inv, z = sb[2 * M + m] * inv;
        atomicAdd(&hC[cellf(x, y, z)], 1);
    }
    for (int i = t; i < N; i += 1024) {
        const float x = qb[i] * inv, y = qb[N + i] * inv, z = qb[2 * N + i] * inv;
        atomicAdd(&hQ[cellf(x, y, z)], 1);
    }
    __syncthreads();

    // inclusive scan (Hillis-Steele over NCELL)
    if (t < NCELL) { oC[t] = hC[t]; oQ[t] = hQ[t]; }
    __syncthreads();
    for (int d = 1; d < NCELL; d <<= 1) {
        int vc = 0, vq = 0;
        if (t < NCELL && t >= d) { vc = oC[t - d]; vq = oQ[t - d]; }
        __syncthreads();
        if (t < NCELL && t >= d) { oC[t] += vc; oQ[t] += vq; }
        __syncthreads();
    }
    if (t < NCELL) {
        const int e = oC[t], h = hC[t];
        off2C[(size_t)b * NCELL + t] = make_int2(e - h, e);
        oC[t] = e - h;
        const int eq = oQ[t] - hQ[t];
        sQex[t] = eq;          // pristine exclusive offsets (group build)
        oQ[t] = eq;            // scatter cursor
    }
    __syncthreads();

    // scatter
    for (int m = t; m < M; m += 1024) {
        const float x = sb[m] * inv, y = sb[M + m] * inv, z = sb[2 * M + m] * inv;
        const int slot = atomicAdd(&oC[cellf(x, y, z)], 1);
        ptsS[(size_t)b * M + slot] = make_float4(x, y, z, fmaf(x, x, fmaf(y, y, z * z)));
        idxS[(size_t)b * M + slot] = m;
    }
    for (int i = t; i < N; i += 1024) {
        const float x = qb[i] * inv, y = qb[N + i] * inv, z = qb[2 * N + i] * inv;
        const int slot = atomicAdd(&oQ[cellf(x, y, z)], 1);
        qS[(size_t)b * N + slot] = make_float4(x, y, z, __int_as_float(i));
    }
    __syncthreads();

    // group table: one group per 64 queries of each super-cell (code>>6).
    // cells of super-cell sc are Morton codes sc*8..sc*8+7 (contiguous).
    if (t < 64) {
        const int sc = t;
        const int qs = sQex[sc * 8];
        const int qe = (sc == 63) ? N : sQex[sc * 8 + 8];
        const int cnt = qe - qs;
        int ng = (cnt + 63) >> 6;
        int incl = ng;
#pragma unroll
        for (int d = 1; d < 64; d <<= 1) {
            const int v = __shfl_up(incl, d, 64);
            if (t >= d) incl += v;
        }
        const int goff = incl - ng;
        for (int k = 0; k < ng; ++k) {
            const int base = k << 6;
            grpTab[(size_t)b * GPB + goff + k] =
                make_int2(qs + base, min(64, cnt - base));
        }
        if (t == 63) grpCnt[b] = incl;
    }
}

// ---------------- main grid kNN: super-cell groups, warm-up + pruned rings ----------------

// scan all candidates of cell CELLIDX through the exact ladder
#define CELLSCAN(CELLIDX)                                                       \
    {                                                                           \
        const int2 oo_ = off2b[CELLIDX];                                        \
        const int base_ = __builtin_amdgcn_readfirstlane(oo_.x);                \
        const int end_ = __builtin_amdgcn_readfirstlane(oo_.y);                 \
        int j_ = base_;                                                         \
        for (; j_ + 4 <= end_; j_ += 4) {                                       \
            const float4 p0_ = Pb[j_];                                          \
            const float4 p1_ = Pb[j_ + 1];                                      \
            const float4 p2_ = Pb[j_ + 2];                                      \
            const float4 p3_ = Pb[j_ + 3];                                      \
            LAD(p0_, j_) LAD(p1_, j_ + 1)                                       \
            LAD(p2_, j_ + 2) LAD(p3_, j_ + 3)                                   \
        }                                                                       \
        for (; j_ < end_; ++j_) {                                               \
            const float4 pp_ = Pb[j_];                                          \
            LAD(pp_, j_)                                                        \
        }                                                                       \
    }

// per-lane z-cell test + scan. needs dxy2, mxy in scope.
#define CELLP(CZ)                                                               \
    {                                                                           \
        const float dzl_ = axdist(qz, (CZ));                                    \
        const float d3_ = fmaf(dzl_, dzl_, dxy2);                               \
        const float cmp_ = fmaf(fminf(e4, bw) + qq, 1.00001f, EPSM);            \
        if (!__all(d3_ > cmp_)) {                                               \
            CELLSCAN(mxy | sp3(CZ))                                             \
        }                                                                       \
    }

__global__ __launch_bounds__(BLOCK, 8)
void knn_cell_kernel(const float4* __restrict__ qS, const float4* __restrict__ ptsS,
                     const int* __restrict__ idxS, const int2* __restrict__ off2C,
                     const int2* __restrict__ grpTab, const int* __restrict__ grpCnt,
                     const float* __restrict__ sflow,
                     float* __restrict__ out, int N, int M, int GPB) {
    __shared__ float sval_d[SLICES * KNN * 64];   // 10 KB
    __shared__ u32   sval_i[SLICES * KNN * 64];   // 10 KB

    const int tid  = threadIdx.x;
    const int lane = tid & 63;
    const int wid  = tid >> 6;
    const int gid  = blockIdx.x;
    const int b    = gid / GPB;
    const int g    = gid - b * GPB;
    if (g >= grpCnt[b]) return;

    const int2 ent = grpTab[(size_t)b * GPB + g];
    const int qbase = ent.x, qcnt = ent.y;
    const int lidx = qbase + (lane < qcnt ? lane : qcnt - 1);   // mirror tail

    const float4 q4 = qS[(size_t)b * N + lidx];
    const float qx = q4.x, qy = q4.y, qz = q4.z;
    const int n = __float_as_int(q4.w);
    const float qq = fmaf(qx, qx, fmaf(qy, qy, qz * qz));

    // wave AABB (mirrored lanes duplicate a real query -> no inflation)
    float wlx = qx, wly = qy, wlz = qz, whx = qx, why = qy, whz = qz;
#pragma unroll
    for (int m = 1; m < 64; m <<= 1) {
        wlx = fminf(wlx, __shfl_xor(wlx, m, 64));
        whx = fmaxf(whx, __shfl_xor(whx, m, 64));
        wly = fminf(wly, __shfl_xor(wly, m, 64));
        why = fmaxf(why, __shfl_xor(why, m, 64));
        wlz = fminf(wlz, __shfl_xor(wlz, m, 64));
        whz = fmaxf(whz, __shfl_xor(whz, m, 64));
    }
    wlx = rfl_f(wlx) - EPSM; whx = rfl_f(whx) + EPSM;
    wly = rfl_f(wly) - EPSM; why = rfl_f(why) + EPSM;
    wlz = rfl_f(wlz) - EPSM; whz = rfl_f(whz) + EPSM;

    const int clx = cidf(wlx), cxh = cidf(whx);
    const int cly = cidf(wly), cyh = cidf(why);
    const int clz = cidf(wlz), czh = cidf(whz);

    float e0 = 1e30f, e1 = 1e30f, e2 = 1e30f, e3 = 1e30f, e4 = 1e30f;
    u32   i0 = 0, i1 = 0, i2 = 0, i3 = 0, i4 = 0;

    const float4* __restrict__ Pb = ptsS + (size_t)b * M;
    const int2* __restrict__ off2b = off2C + (size_t)b * NCELL;

    // per-lane home-cell warm-up: value-only ladder -> upper bound bw on the
    // lane's 5th-best d2' (subset bound; real ladder untouched).
    float bw;
    {
        const int2 ho = off2b[cellf(qx, qy, qz)];
        float v0 = 1e30f, v1 = 1e30f, v2 = 1e30f, v3 = 1e30f, v4 = 1e30f;
        for (int j = ho.x; j < ho.y; ++j) {
            const float4 p = Pb[j];
            float t = qx * p.x;
            t = fmaf(qy, p.y, t);
            t = fmaf(qz, p.z, t);
            float c = fmaf(-2.0f, t, p.w);
            float mn;
            mn = fminf(v0, c); c = fmaxf(v0, c); v0 = mn;
            mn = fminf(v1, c); c = fmaxf(v1, c); v1 = mn;
            mn = fminf(v2, c); c = fmaxf(v2, c); v2 = mn;
            mn = fminf(v3, c); c = fmaxf(v3, c); v3 = mn;
            v4 = fminf(v4, c);
        }
        bw = v4;
    }

    int ctr = 0;
    // ---- phase 1: span-box scan (cell ownership RR, pruned by bw) ----
    for (int cx = clx; cx <= cxh; ++cx) {
        const float dxl = axdist(qx, cx);
        const float dxx = dxl * dxl;
        const int mx = sp3(cx) << 2;
        for (int cy = cly; cy <= cyh; ++cy) {
            const float dyl = axdist(qy, cy);
            const float dxy2 = fmaf(dyl, dyl, dxx);
            const int mxy = mx | (sp3(cy) << 1);
            for (int cz = clz; cz <= czh; ++cz) {
                if (((ctr++) & 7) == wid) { CELLP(cz) }
            }
        }
    }
    // ---- phase 2: expanding rings; deterministic termination from the
    // own-wave lane-max of min(e4,bw)+qq. hmin = 1 (fixed box). ----
    float TwR = 1e30f;
    for (int r = 1; r <= GRID; ++r) {
        float own = fminf(e4, bw) + qq;
#pragma unroll
        for (int mm = 1; mm < 64; mm <<= 1) own = fmaxf(own, __shfl_xor(own, mm, 64));
        TwR = fminf(TwR, rfl_f(own));
        if (r >= 2) {
            const float bd = (float)(r - 1) - EPSM;
            if (bd * bd > fmaf(TwR, 1.00001f, EPSM)) break;
        }
        const int x0 = clx - r < 0 ? 0 : clx - r;
        const int x1 = cxh + r > GRID - 1 ? GRID - 1 : cxh + r;
        const int y0 = cly - r < 0 ? 0 : cly - r;
        const int y1 = cyh + r > GRID - 1 ? GRID - 1 : cyh + r;
        const int z0 = clz - r < 0 ? 0 : clz - r;
        const int z1 = czh + r > GRID - 1 ? GRID - 1 : czh + r;
        for (int cx = x0; cx <= x1; ++cx) {
            const int rx = cx < clx ? clx - cx : (cx > cxh ? cx - cxh : 0);
            const float dxl = axdist(qx, cx);
            const float dxx = dxl * dxl;
            const int mx = sp3(cx) << 2;
            for (int cy = y0; cy <= y1; ++cy) {
                const int ry = cy < cly ? cly - cy : (cy > cyh ? cy - cyh : 0);
                if (((ctr++) & 7) == wid) {
                    const float dyl = axdist(qy, cy);
                    const float dxy2 = fmaf(dyl, dyl, dxx);
                    const float cmpc = fmaf(fminf(e4, bw) + qq, 1.00001f, EPSM);
                    if (!__all(dxy2 > cmpc)) {
                        const int mxy = mx | (sp3(cy) << 1);
                        if ((rx > ry ? rx : ry) == r) {
                            for (int cz = z0; cz <= z1; ++cz) { CELLP(cz) }
                        } else {
                            if (clz - r >= 0) { CELLP(clz - r) }
                            if (czh + r <= GRID - 1) { CELLP(czh + r) }
                        }
                    }
                }
            }
        }
    }

    sval_d[(wid * KNN + 0) * 64 + lane] = e0;  sval_i[(wid * KNN + 0) * 64 + lane] = i0;
    sval_d[(wid * KNN + 1) * 64 + lane] = e1;  sval_i[(wid * KNN + 1) * 64 + lane] = i1;
    sval_d[(wid * KNN + 2) * 64 + lane] = e2;  sval_i[(wid * KNN + 2) * 64 + lane] = i2;
    sval_d[(wid * KNN + 3) * 64 + lane] = e3;  sval_i[(wid * KNN + 3) * 64 + lane] = i3;
    sval_d[(wid * KNN + 4) * 64 + lane] = e4;  sval_i[(wid * KNN + 4) * 64 + lane] = i4;
    __syncthreads();

    if (wid == 0) {
        float m0 = 1e30f, m1 = 1e30f, m2 = 1e30f, m3 = 1e30f, m4 = 1e30f;
        u32 g0 = 0, g1 = 0, g2 = 0, g3 = 0, g4 = 0;
#pragma unroll
        for (int w = 0; w < SLICES; ++w) {
#pragma unroll
            for (int k = 0; k < KNN; ++k) {
                float c = sval_d[(w * KNN + k) * 64 + lane];
                u32 ci = sval_i[(w * KNN + k) * 64 + lane];
                CE_FULL(m0, g0, c, ci)
                CE_FULL(m1, g1, c, ci)
                CE_FULL(m2, g2, c, ci)
                CE_FULL(m3, g3, c, ci)
                CE_LAST(m4, g4, c, ci)
            }
        }

        if (lane < qcnt) {
            const float d0 = sqrtf(fmaxf(m0 + qq, 1e-12f));
            const float d1 = sqrtf(fmaxf(m1 + qq, 1e-12f));
            const float d2 = sqrtf(fmaxf(m2 + qq, 1e-12f));
            const float d3 = sqrtf(fmaxf(m3 + qq, 1e-12f));
            const float d4 = sqrtf(fmaxf(m4 + qq, 1e-12f));
            const float w0 = 1.0f;
            const float w1 = expf(d0 - d1);
            const float w2 = expf(d0 - d2);
            const float w3 = expf(d0 - d3);
            const float w4 = expf(d0 - d4);
            const float inv_wsum = 1.0f / (w0 + w1 + w2 + w3 + w4);

            const int* __restrict__ idxb = idxS + (size_t)b * M;
            const int o0 = idxb[g0], o1 = idxb[g1], o2 = idxb[g2], o3 = idxb[g3], o4 = idxb[g4];
            const float* fb = sflow + (size_t)b * 3 * M;
            float ax = 0.f, ay = 0.f, az = 0.f;
            ax = fmaf(w0, fb[o0], ax); ay = fmaf(w0, fb[M + o0], ay); az = fmaf(w0, fb[2 * M + o0], az);
            ax = fmaf(w1, fb[o1], ax); ay = fmaf(w1, fb[M + o1], ay); az = fmaf(w1, fb[2 * M + o1], az);
            ax = fmaf(w2, fb[o2], ax); ay = fmaf(w2, fb[M + o2], ay); az = fmaf(w2, fb[2 * M + o2], az);
            ax = fmaf(w3, fb[o3], ax); ay = fmaf(w3, fb[M + o3], ay); az = fmaf(w3, fb[2 * M + o3], az);
            ax = fmaf(w4, fb[o4], ax); ay = fmaf(w4, fb[M + o4], ay); az = fmaf(w4, fb[2 * M + o4], az);

            float* ob = out + (size_t)b * 3 * N;
            ob[n]         = ax * inv_wsum;
            ob[N + n]     = ay * inv_wsum;
            ob[2 * N + n] = az * inv_wsum;
        }
    }
}

extern "C" void kernel_launch(void* const* d_in, const int* in_sizes, int n_in,
                              void* d_out, int out_size, void* d_ws, size_t ws_size,
                              hipStream_t stream) {
    const float* xyz   = (const float*)d_in[0];
    const float* sxyz  = (const float*)d_in[1];
    const float* sflow = (const float*)d_in[2];
    const int*   rf    = (const int*)d_in[3];

    const int B = 4;
    const int N = in_sizes[0] / (3 * B);    // 16384
    const int M = in_sizes[1] / (3 * B);    // 4096
    float* out = (float*)d_out;
    const int GPB = N / 64 + 64;            // max groups per batch (<= 320)

    // workspace layout
    size_t o = 0;
    float4* ptsS  = (float4*)((char*)d_ws + o); o += (size_t)B * M * sizeof(float4);
    float4* qS    = (float4*)((char*)d_ws + o); o += (size_t)B * N * sizeof(float4);
    int*   idxS   = (int*)((char*)d_ws + o);    o += (size_t)B * M * 4;
    int2*  off2C  = (int2*)((char*)d_ws + o);   o += (size_t)B * NCELL * 8;
    int2*  grpTab = (int2*)((char*)d_ws + o);   o += (size_t)B * GPB * 8;
    int*   grpCnt = (int*)((char*)d_ws + o);    o += 64;
    const size_t need = o;

    if (ws_size >= need && (N % 64) == 0) {
        prep_cell_kernel<<<dim3(B), dim3(1024), 0, stream>>>(
            xyz, sxyz, rf, off2C, ptsS, qS, idxS, grpTab, grpCnt, N, M, GPB);
        knn_cell_kernel<<<dim3(B * GPB), dim3(BLOCK), 0, stream>>>(
            qS, ptsS, idxS, off2C, grpTab, grpCnt, sflow, out, N, M, GPB);
    } else {
        const dim3 grid(B * (N / 64));
        const dim3 block(BLOCK);
        const size_t needOld = (size_t)B * M * sizeof(float4);
        if (ws_size >= needOld) {
            float4* pts = (float4*)d_ws;
            prep_kernel<<<dim3((B * M + 255) / 256), dim3(256), 0, stream>>>(
                sxyz, rf, pts, M, B * M);
            knn_kernel<true><<<grid, block, 0, stream>>>(xyz, sxyz, sflow, rf, pts, out, N, M);
        } else {
            knn_kernel<false><<<grid, block, 0, stream>>>(xyz, sxyz, sflow, rf, nullptr, out, N, M);
        }
    }
}